// Round 3
// baseline (621.713 us; speedup 1.0000x reference)
//
#include <hip/hip_runtime.h>
#include <math.h>

#define B_  64
#define S_  2048
#define D_  512
#define NH_ 8

// ---------------- workspace layout (float offsets) ----------------
static const size_t OFF_WKEFF  = 0;                         // 8*512
static const size_t OFF_SSUM   = 4096;                      // 64*512  } zeroed
static const size_t OFF_PSUM   = 36864;                     // 64*512  } zeroed
static const size_t OFF_LSUM   = 69632;                     // 64*8    } zeroed
static const size_t OFF_XARAW  = 70144;                     // 64*8*512} zeroed (ends 332288)
static const size_t OFF_FUSED  = 332288;
static const size_t OFF_FM     = 365056;
static const size_t OFF_MEANT  = 397824;
static const size_t OFF_CATSP  = 430592;                    // 64*1024
static const size_t OFF_CLOST  = 496128;
static const size_t OFF_G1     = 528896;
static const size_t OFF_CTX    = 561664;
static const size_t OFF_HC     = 594432;
static const size_t OFF_S3     = 627200;                    // 64*4
static const size_t OFF_HEADIN = 627456;                    // 64*520
static const size_t OFF_HS     = 660736;
static const size_t OFF_HF     = 693504;
static const size_t OFF_MINFO  = 726272;                    // ints

#define NZERO 328192   // ssum+psum+lsum+xaraw contiguous

// ---------------- fused prep: zero accumulators + wkeff + mask scan ----------------
// blocks [0,1282): zero; [1282,1298): wkeff; [1298,1362): mask scan
__global__ __launch_bounds__(256) void k_prep(const float* __restrict__ Wk,
                                              const float* __restrict__ q,
                                              const int* __restrict__ mask,
                                              float* __restrict__ zbase,
                                              float* __restrict__ wkeff,
                                              int* __restrict__ minfo) {
    int bx = blockIdx.x, tid = threadIdx.x;
    if (bx < 1282) {
        int i = bx * 256 + tid;
        if (i < NZERO) zbase[i] = 0.f;
        return;
    }
    if (bx < 1298) {
        int idx = (bx - 1282) * 256 + tid;       // [0,4096)
        int h = idx >> 9, e = idx & 511;
        float s = 0.f;
        #pragma unroll 8
        for (int d = 0; d < 64; ++d) s = fmaf(Wk[e * 512 + h * 64 + d], q[h * 64 + d], s);
        wkeff[h * 512 + e] = s * 0.125f;
        return;
    }
    {
        int b = bx - 1298;
        __shared__ int sh[256];
        int m8[8]; int cnt = 0; int s0 = tid * 8;
        #pragma unroll
        for (int i = 0; i < 8; ++i) { m8[i] = mask[b * S_ + s0 + i] > 0; cnt += m8[i]; }
        sh[tid] = cnt; __syncthreads();
        for (int off = 1; off < 256; off <<= 1) {
            int add = (tid >= off) ? sh[tid - off] : 0;
            __syncthreads();
            sh[tid] += add;
            __syncthreads();
        }
        int total  = sh[255];
        int before = sh[tid] - cnt;
        int split  = max(1, (int)floorf((float)total * 0.6f));
        int cum = before;
        #pragma unroll
        for (int i = 0; i < 8; ++i) {
            if (m8[i]) {
                cum++;
                if (cum == split) minfo[b * 8 + 2] = s0 + i;
                if (cum == total) minfo[b * 8 + 3] = s0 + i;
            }
        }
        if (tid == 0) { minfo[b * 8 + 0] = total; minfo[b * 8 + 1] = split; }
    }
}

// ---------------- single heavy pass over x ----------------
// grid (64,16); block = 128 tokens; 4 waves read the same tokens (L1 broadcast),
// wave w owns heads {2w,2w+1}. Lane owns 8 contiguous cols. 4 tokens/iter with
// prefetch (8 dwordx4 in flight, 8 interleaved 6-step butterflies). Masks via
// one __ballot per 64-token half. Accumulators flushed with global f32 atomics
// directly into xa_raw (no xapart round-trip, no LDS at all).
__global__ __launch_bounds__(256, 3) void k_main(const float* __restrict__ x,
                                                 const int* __restrict__ mask,
                                                 const float* __restrict__ wkeff,
                                                 const int* __restrict__ minfo,
                                                 float* __restrict__ ssum,
                                                 float* __restrict__ psum,
                                                 float* __restrict__ lsum,
                                                 float* __restrict__ xaraw) {
    const int b = blockIdx.x, chunk = blockIdx.y;
    const int tid = threadIdx.x, hg = tid >> 6, lane = tid & 63;
    const int h0 = hg * 2;
    const int col0 = lane * 8;

    float wk0[8], wk1[8];
    #pragma unroll
    for (int i = 0; i < 8; ++i) {
        wk0[i] = wkeff[h0 * 512 + col0 + i];
        wk1[i] = wkeff[(h0 + 1) * 512 + col0 + i];
    }

    const int boundary = minfo[b * 8 + 2];
    const int sb = chunk * 128;
    const int* mb = mask + b * S_;
    unsigned long long bm0 = __ballot(mb[sb + lane] > 0);
    unsigned long long bm1 = __ballot(mb[sb + 64 + lane] > 0);

    float acc0[8], acc1[8], sacc[8], pacc[8];
    #pragma unroll
    for (int i = 0; i < 8; ++i) { acc0[i] = 0.f; acc1[i] = 0.f; sacc[i] = 0.f; pacc[i] = 0.f; }
    float l0 = 0.f, l1 = 0.f;

    const float* base = x + (size_t)b * (S_ * D_) + (size_t)sb * D_ + col0;

    float4 P[8];
    #pragma unroll
    for (int k = 0; k < 4; ++k) {
        P[2 * k]     = *(const float4*)(base + (size_t)k * D_);
        P[2 * k + 1] = *(const float4*)(base + (size_t)k * D_ + 4);
    }

    for (int t = 0; t < 128; t += 4) {
        float cur[4][8];
        #pragma unroll
        for (int k = 0; k < 4; ++k) {
            cur[k][0] = P[2 * k].x;     cur[k][1] = P[2 * k].y;
            cur[k][2] = P[2 * k].z;     cur[k][3] = P[2 * k].w;
            cur[k][4] = P[2 * k + 1].x; cur[k][5] = P[2 * k + 1].y;
            cur[k][6] = P[2 * k + 1].z; cur[k][7] = P[2 * k + 1].w;
        }
        if (t + 4 < 128) {
            const float* nb = base + (size_t)(t + 4) * D_;
            #pragma unroll
            for (int k = 0; k < 4; ++k) {
                P[2 * k]     = *(const float4*)(nb + (size_t)k * D_);
                P[2 * k + 1] = *(const float4*)(nb + (size_t)k * D_ + 4);
            }
        }
        // per-lane partial scores: 4 tokens x 2 heads
        float s8[8];
        #pragma unroll
        for (int k = 0; k < 4; ++k) {
            float a0 = cur[k][0] * wk0[0];
            float a1 = cur[k][0] * wk1[0];
            #pragma unroll
            for (int i = 1; i < 8; ++i) {
                a0 = fmaf(cur[k][i], wk0[i], a0);
                a1 = fmaf(cur[k][i], wk1[i], a1);
            }
            s8[k] = a0; s8[4 + k] = a1;
        }
        // 8 interleaved butterflies across 64 lanes
        #pragma unroll
        for (int d = 1; d < 64; d <<= 1) {
            #pragma unroll
            for (int v = 0; v < 8; ++v) s8[v] += __shfl_xor(s8[v], d, 64);
        }
        unsigned long long bsel = (t < 64) ? bm0 : bm1;
        float w0[4], w1[4];
        #pragma unroll
        for (int k = 0; k < 4; ++k) {
            bool mm = ((bsel >> ((t + k) & 63)) & 1ULL) != 0;
            w0[k] = mm ? __expf(s8[k])     : 0.f;
            w1[k] = mm ? __expf(s8[4 + k]) : 0.f;
        }
        l0 += (w0[0] + w0[1]) + (w0[2] + w0[3]);
        l1 += (w1[0] + w1[1]) + (w1[2] + w1[3]);
        #pragma unroll
        for (int i = 0; i < 8; ++i) {
            float a = acc0[i], c = acc1[i];
            #pragma unroll
            for (int k = 0; k < 4; ++k) {
                a = fmaf(w0[k], cur[k][i], a);
                c = fmaf(w1[k], cur[k][i], c);
            }
            acc0[i] = a; acc1[i] = c;
        }
        if (hg == 0) {
            float fs[4], fp[4];
            #pragma unroll
            for (int k = 0; k < 4; ++k) {
                bool mm = ((bsel >> ((t + k) & 63)) & 1ULL) != 0;
                int sg = sb + t + k;
                fs[k] = (mm && sg <= boundary) ? 1.f : 0.f;
                fp[k] = (mm && sg >  boundary) ? 1.f : 0.f;
            }
            #pragma unroll
            for (int i = 0; i < 8; ++i) {
                float a = sacc[i], c = pacc[i];
                #pragma unroll
                for (int k = 0; k < 4; ++k) {
                    a = fmaf(fs[k], cur[k][i], a);
                    c = fmaf(fp[k], cur[k][i], c);
                }
                sacc[i] = a; pacc[i] = c;
            }
        }
    }

    float* xr0 = xaraw + ((size_t)(b * 8 + h0)) * 512 + col0;
    float* xr1 = xr0 + 512;
    #pragma unroll
    for (int i = 0; i < 8; ++i) {
        atomicAdd(&xr0[i], acc0[i]);
        atomicAdd(&xr1[i], acc1[i]);
    }
    if (lane == 0) {
        atomicAdd(&lsum[b * 8 + h0],     l0);
        atomicAdd(&lsum[b * 8 + h0 + 1], l1);
    }
    if (hg == 0) {
        #pragma unroll
        for (int i = 0; i < 8; ++i) {
            atomicAdd(&ssum[b * 512 + col0 + i], sacc[i]);
            atomicAdd(&psum[b * 512 + col0 + i], pacc[i]);
        }
    }
}

// mean_tok, setup_mean, punch_mean (punch_cnt==0 -> last valid token), clost_stream
__global__ __launch_bounds__(256) void k_means(const float* __restrict__ x,
                                               const float* __restrict__ ssum,
                                               const float* __restrict__ psum,
                                               const int* __restrict__ minfo,
                                               float* __restrict__ meantok,
                                               float* __restrict__ catsp,
                                               float* __restrict__ clost) {
    int b = blockIdx.x;
    int e = blockIdx.y * 256 + threadIdx.x;
    int total = minfo[b * 8 + 0], split = minfo[b * 8 + 1], last = minfo[b * 8 + 3];
    int pcnt = total - split;
    float ssv = ssum[b * 512 + e], psv = psum[b * 512 + e];
    float mt = (ssv + psv) / (float)total;
    float sm = ssv / (float)split;
    float pm = (pcnt > 0) ? psv / (float)pcnt : x[((size_t)b * S_ + last) * D_ + e];
    meantok[b * 512 + e] = mt;
    catsp[b * 1024 + e] = sm;
    catsp[b * 1024 + 512 + e] = pm;
    clost[b * 512 + e] = 0.5f * (sm + pm);
}

// ---------------- batched GEMV: up to 3 ops per launch (blockIdx.z) ----------------
// grid (64, 8, nz). Block: batch b, 64 outputs, 4-way K-split (256 thr).
// A row staged in LDS; headmode: A row = xaraw[b, head=jg] * (1/lsum[b,jg]).
__global__ __launch_bounds__(256) void k_gemv3(
    const float* lsum,
    const float* A0_, int lda0, const float* W0_, const float* bi0_, float* o0_, int K0, int r0, int hm0,
    const float* A1_, int lda1, const float* W1_, const float* bi1_, float* o1_, int K1, int r1, int hm1,
    const float* A2_, int lda2, const float* W2_, const float* bi2_, float* o2_, int K2, int r2, int hm2) {
    const float* A; const float* W; const float* bias; float* out;
    int lda, K, relu_, hm;
    int z = blockIdx.z;
    if (z == 0)      { A = A0_; lda = lda0; W = W0_; bias = bi0_; out = o0_; K = K0; relu_ = r0; hm = hm0; }
    else if (z == 1) { A = A1_; lda = lda1; W = W1_; bias = bi1_; out = o1_; K = K1; relu_ = r1; hm = hm1; }
    else             { A = A2_; lda = lda2; W = W2_; bias = bi2_; out = o2_; K = K2; relu_ = r2; hm = hm2; }

    int b = blockIdx.x, jg = blockIdx.y;
    int tid = threadIdx.x, jl = tid & 63, part = tid >> 6;
    int j = jg * 64 + jl;
    const float* a = hm ? (A + ((size_t)(b * 8 + jg)) * 512) : (A + (size_t)b * lda);
    float scale = hm ? (1.f / lsum[b * 8 + jg]) : 1.f;

    __shared__ float sha[1024];
    for (int e = tid; e < K; e += 256) sha[e] = a[e] * scale;
    __syncthreads();

    int Kq = (K + 3) >> 2;
    int e0 = part * Kq, e1 = min(K, e0 + Kq);
    float acc = 0.f;
    int e = e0;
    for (; e + 8 <= e1; e += 8) {
        #pragma unroll
        for (int u = 0; u < 8; ++u)
            acc = fmaf(sha[e + u], W[(size_t)(e + u) * 512 + j], acc);
    }
    for (; e < e1; ++e) acc = fmaf(sha[e], W[(size_t)e * 512 + j], acc);

    __shared__ float shr[256];
    shr[tid] = acc;
    __syncthreads();
    if (part == 0) {
        float s = shr[jl] + shr[jl + 64] + shr[jl + 128] + shr[jl + 192];
        if (bias) s += bias[j];
        if (relu_) s = fmaxf(s, 0.f);
        out[(size_t)b * 512 + j] = s;
    }
}

// fused: scalar heads (tom_hp/inc/clost_prob) + stream mixing + headin build
__global__ __launch_bounds__(256) void k_scalmix(const float* __restrict__ fm,
                                                 const float* __restrict__ ctx,
                                                 const float* __restrict__ hc,
                                                 const float* __restrict__ clost,
                                                 const float* __restrict__ w_hp,  const float* __restrict__ b_hp,
                                                 const float* __restrict__ w_inc, const float* __restrict__ b_inc,
                                                 const float* __restrict__ wc2,   const float* __restrict__ bc2,
                                                 const float* __restrict__ U,
                                                 const float* __restrict__ V,
                                                 float* __restrict__ s3,
                                                 float* __restrict__ headin) {
    int b = blockIdx.x, tid = threadIdx.x;
    float a0 = 0.f, a1 = 0.f, a2 = 0.f;
    for (int e = tid; e < 512; e += 256) {
        a0 = fmaf(fm[b * 512 + e],  w_hp[e],  a0);
        a1 = fmaf(ctx[b * 512 + e], w_inc[e], a1);
        a2 = fmaf(hc[b * 512 + e],  wc2[e],   a2);
    }
    __shared__ float r[3][256];
    r[0][tid] = a0; r[1][tid] = a1; r[2][tid] = a2;
    __syncthreads();
    for (int off = 128; off > 0; off >>= 1) {
        if (tid < off) {
            r[0][tid] += r[0][tid + off];
            r[1][tid] += r[1][tid + off];
            r[2][tid] += r[2][tid + off];
        }
        __syncthreads();
    }
    __shared__ float s3sh[3];
    if (tid == 0) {
        s3sh[0] = 1.f / (1.f + __expf(-(r[0][0] + b_hp[0])));
        s3sh[1] = 1.f / (1.f + __expf(-(r[1][0] + b_inc[0])));
        s3sh[2] = 1.f / (1.f + __expf(-(r[2][0] + bc2[0])));
        s3[b * 4 + 0] = s3sh[0];
        s3[b * 4 + 1] = s3sh[1];
        s3[b * 4 + 2] = s3sh[2];
    }
    __syncthreads();
    float M3[3][3];
    #pragma unroll
    for (int s = 0; s < 3; ++s)
        #pragma unroll
        for (int t = 0; t < 3; ++t) {
            float acc = (s == t) ? 1.f : 0.f;
            #pragma unroll
            for (int r4 = 0; r4 < 4; ++r4) acc = fmaf(U[s * 4 + r4], V[r4 * 3 + t], acc);
            M3[s][t] = acc;
        }
    float mx[3][2];
    #pragma unroll
    for (int kk = 0; kk < 2; ++kk) {
        int e = tid + kk * 256;
        float t0 = fm[b * 512 + e], t1 = ctx[b * 512 + e], t2 = clost[b * 512 + e];
        #pragma unroll
        for (int s = 0; s < 3; ++s) mx[s][kk] = M3[s][0] * t0 + M3[s][1] * t1 + M3[s][2] * t2;
    }
    #pragma unroll
    for (int s = 0; s < 3; ++s) r[s][tid] = mx[s][0] * mx[s][0] + mx[s][1] * mx[s][1];
    __syncthreads();
    for (int off = 128; off > 0; off >>= 1) {
        if (tid < off) {
            r[0][tid] += r[0][tid + off];
            r[1][tid] += r[1][tid + off];
            r[2][tid] += r[2][tid + off];
        }
        __syncthreads();
    }
    __shared__ float nrm[3];
    if (tid < 3) nrm[tid] = sqrtf(r[tid][0]) + 1e-6f;
    __syncthreads();
    #pragma unroll
    for (int kk = 0; kk < 2; ++kk) {
        int e = tid + kk * 256;
        float p = (mx[0][kk] / nrm[0] + mx[1][kk] / nrm[1] + mx[2][kk] / nrm[2]) * (1.f / 3.f);
        headin[b * 520 + e] = p;
    }
    if (tid < 3) headin[b * 520 + 512 + tid] = s3sh[tid];
}

__global__ __launch_bounds__(256) void k_logit(const float* __restrict__ hs,
                                               const float* __restrict__ hf,
                                               const float* __restrict__ ws2, const float* __restrict__ bs2,
                                               const float* __restrict__ wf2, const float* __restrict__ bf2,
                                               const float* __restrict__ s3,
                                               float* __restrict__ out) {
    int b = blockIdx.x, tid = threadIdx.x;
    float a = 0.f, c = 0.f;
    for (int e = tid; e < 512; e += 256) {
        a = fmaf(hs[b * 512 + e], ws2[e], a);
        c = fmaf(hf[b * 512 + e], wf2[e], c);
    }
    __shared__ float r[2][256];
    r[0][tid] = a; r[1][tid] = c;
    __syncthreads();
    for (int off = 128; off > 0; off >>= 1) {
        if (tid < off) { r[0][tid] += r[0][tid + off]; r[1][tid] += r[1][tid + off]; }
        __syncthreads();
    }
    if (tid == 0) {
        float sev = r[0][0] + bs2[0];
        float fl  = r[1][0] + bf2[0];
        float p = (s3[b * 4] + s3[b * 4 + 1] + s3[b * 4 + 2]) * (1.f / 3.f);
        p = fminf(fmaxf(p, 1e-4f), 1.f - 1e-4f);
        out[b] = fl + 0.5f * sev + 0.1f * logf(p / (1.f - p));
    }
}

extern "C" void kernel_launch(void* const* d_in, const int* in_sizes, int n_in,
                              void* d_out, int out_size, void* d_ws, size_t ws_size,
                              hipStream_t stream) {
    const float* x     = (const float*)d_in[0];
    const int*   mask  = (const int*)d_in[1];
    const float* Wk    = (const float*)d_in[2];
    const float* Wv    = (const float*)d_in[3];
    const float* q_tom = (const float*)d_in[4];
    const float* Wtf   = (const float*)d_in[5];
    const float* w_hp  = (const float*)d_in[6];
    const float* b_hp  = (const float*)d_in[7];
    const float* Wg1   = (const float*)d_in[8];
    const float* bg1   = (const float*)d_in[9];
    const float* Wg2   = (const float*)d_in[10];
    const float* bg2   = (const float*)d_in[11];
    const float* w_inc = (const float*)d_in[12];
    const float* b_inc = (const float*)d_in[13];
    const float* Wc1   = (const float*)d_in[14];
    const float* bc1   = (const float*)d_in[15];
    const float* wc2   = (const float*)d_in[16];
    const float* bc2   = (const float*)d_in[17];
    const float* U     = (const float*)d_in[18];
    const float* V     = (const float*)d_in[19];
    const float* Ws1   = (const float*)d_in[20];
    const float* bs1   = (const float*)d_in[21];
    const float* ws2   = (const float*)d_in[22];
    const float* bs2   = (const float*)d_in[23];
    const float* Wf1   = (const float*)d_in[24];
    const float* bf1   = (const float*)d_in[25];
    const float* wf2   = (const float*)d_in[26];
    const float* bf2   = (const float*)d_in[27];

    float* ws      = (float*)d_ws;
    float* wkeff   = ws + OFF_WKEFF;
    float* ssum    = ws + OFF_SSUM;
    float* psum    = ws + OFF_PSUM;
    float* lsum    = ws + OFF_LSUM;
    float* xaraw   = ws + OFF_XARAW;
    float* fused   = ws + OFF_FUSED;
    float* fm      = ws + OFF_FM;
    float* meantok = ws + OFF_MEANT;
    float* catsp   = ws + OFF_CATSP;
    float* clost   = ws + OFF_CLOST;
    float* g1      = ws + OFF_G1;
    float* ctxb    = ws + OFF_CTX;
    float* hc      = ws + OFF_HC;
    float* s3      = ws + OFF_S3;
    float* headin  = ws + OFF_HEADIN;
    float* hsb     = ws + OFF_HS;
    float* hfb     = ws + OFF_HF;
    int*   minfo   = (int*)(ws + OFF_MINFO);
    float* out     = (float*)d_out;

    hipLaunchKernelGGL(k_prep,   dim3(1362),     dim3(256), 0, stream, Wk, q_tom, mask, ssum, wkeff, minfo);
    hipLaunchKernelGGL(k_main,   dim3(64, 16),   dim3(256), 0, stream, x, mask, wkeff, minfo,
                       ssum, psum, lsum, xaraw);
    hipLaunchKernelGGL(k_means,  dim3(64, 2),    dim3(256), 0, stream, x, ssum, psum, minfo,
                       meantok, catsp, clost);
    // stage A: fused = (xaraw/l)@Wv ; g1 = relu(meantok@Wg1+bg1) ; hc = relu(catsp@Wc1+bc1)
    hipLaunchKernelGGL(k_gemv3,  dim3(64, 8, 3), dim3(256), 0, stream, lsum,
                       xaraw, 0, Wv, (const float*)nullptr, fused, 512, 0, 1,
                       meantok, 512, Wg1, bg1, g1, 512, 1, 0,
                       catsp, 1024, Wc1, bc1, hc, 1024, 1, 0);
    // stage B: fm = fused@Wtf ; ctx = g1@Wg2+bg2
    hipLaunchKernelGGL(k_gemv3,  dim3(64, 8, 2), dim3(256), 0, stream, lsum,
                       fused, 512, Wtf, (const float*)nullptr, fm, 512, 0, 0,
                       g1, 512, Wg2, bg2, ctxb, 512, 0, 0,
                       (const float*)nullptr, 0, (const float*)nullptr, (const float*)nullptr,
                       (float*)nullptr, 0, 0, 0);
    hipLaunchKernelGGL(k_scalmix, dim3(64),      dim3(256), 0, stream, fm, ctxb, hc, clost,
                       w_hp, b_hp, w_inc, b_inc, wc2, bc2, U, V, s3, headin);
    // stage D: hs = relu(headin@Ws1+bs1) ; hf = relu(headin@Wf1+bf1)
    hipLaunchKernelGGL(k_gemv3,  dim3(64, 8, 2), dim3(256), 0, stream, lsum,
                       headin, 520, Ws1, bs1, hsb, 515, 1, 0,
                       headin, 520, Wf1, bf1, hfb, 515, 1, 0,
                       (const float*)nullptr, 0, (const float*)nullptr, (const float*)nullptr,
                       (float*)nullptr, 0, 0, 0);
    hipLaunchKernelGGL(k_logit,  dim3(64),       dim3(256), 0, stream, hsb, hfb, ws2, bs2, wf2, bf2, s3, out);
}

// Round 4
// 494.191 us; speedup vs baseline: 1.2580x; 1.2580x over previous
//
#include <hip/hip_runtime.h>
#include <math.h>

#define B_  64
#define S_  2048
#define D_  512
#define NH_ 8

// ---------------- workspace layout (float offsets) ----------------
// part buffer: per (b,chunk): 10 rows x 512 (8 heads exp-weighted sums, setup sum, punch sum)
static const size_t OFF_WKEFF  = 0;                          // 4096
static const size_t OFF_XPART  = 4096;                       // 64*16*10*512 = 5242880
static const size_t OFF_LPART  = 5246976;                    // 64*16*8
static const size_t OFF_XA     = 5255168;                    // 64*8*512 (raw, undivided)
static const size_t OFF_SSUM   = 5517312;                    // 64*512
static const size_t OFF_PSUM   = 5550080;                    // 64*512
static const size_t OFF_FUSED  = 5582848;
static const size_t OFF_FM     = 5615616;
static const size_t OFF_MEANT  = 5648384;
static const size_t OFF_CATSP  = 5681152;                    // 64*1024
static const size_t OFF_CLOST  = 5746688;
static const size_t OFF_G1     = 5779456;
static const size_t OFF_CTX    = 5812224;
static const size_t OFF_HC     = 5844992;
static const size_t OFF_S3     = 5877760;                    // 64*4
static const size_t OFF_HEADIN = 5878016;                    // 64*520
static const size_t OFF_HS     = 5911296;
static const size_t OFF_HF     = 5944064;
static const size_t OFF_MINFO  = 5976832;                    // ints

// wave64 all-sum via DPP (VALU pipe only — no LDS/ds_swizzle traffic).
// Canonical gfx9 sequence: row_shr 1/2/4/8 (prefix within 16-lane rows),
// row_bcast:15 (rm=0xa), row_bcast:31 (rm=0xc); total lands in lane 63.
__device__ __forceinline__ float wave_sum64(float v) {
#define DPP_STEP(ctrl, rm) \
    v += __int_as_float(__builtin_amdgcn_update_dpp(0, __float_as_int(v), (ctrl), (rm), 0xf, true))
    DPP_STEP(0x111, 0xf);   // row_shr:1
    DPP_STEP(0x112, 0xf);   // row_shr:2
    DPP_STEP(0x114, 0xf);   // row_shr:4
    DPP_STEP(0x118, 0xf);   // row_shr:8
    DPP_STEP(0x142, 0xa);   // row_bcast:15 -> rows 1,3
    DPP_STEP(0x143, 0xc);   // row_bcast:31 -> rows 2,3
#undef DPP_STEP
    return __int_as_float(__builtin_amdgcn_readlane(__float_as_int(v), 63));
}

// ---------------- prep: wkeff + mask scan (no zeroing needed) ----------------
// blocks [0,16): wkeff; [16,80): per-batch mask scan
__global__ __launch_bounds__(256) void k_prep(const float* __restrict__ Wk,
                                              const float* __restrict__ q,
                                              const int* __restrict__ mask,
                                              float* __restrict__ wkeff,
                                              int* __restrict__ minfo) {
    int bx = blockIdx.x, tid = threadIdx.x;
    if (bx < 16) {
        int idx = bx * 256 + tid;               // [0,4096)
        int h = idx >> 9, e = idx & 511;
        float s = 0.f;
        #pragma unroll 8
        for (int d = 0; d < 64; ++d) s = fmaf(Wk[e * 512 + h * 64 + d], q[h * 64 + d], s);
        wkeff[h * 512 + e] = s * 0.125f;
        return;
    }
    {
        int b = bx - 16;
        __shared__ int sh[256];
        int m8[8]; int cnt = 0; int s0 = tid * 8;
        #pragma unroll
        for (int i = 0; i < 8; ++i) { m8[i] = mask[b * S_ + s0 + i] > 0; cnt += m8[i]; }
        sh[tid] = cnt; __syncthreads();
        for (int off = 1; off < 256; off <<= 1) {
            int add = (tid >= off) ? sh[tid - off] : 0;
            __syncthreads();
            sh[tid] += add;
            __syncthreads();
        }
        int total  = sh[255];
        int before = sh[tid] - cnt;
        int split  = max(1, (int)floorf((float)total * 0.6f));
        int cum = before;
        #pragma unroll
        for (int i = 0; i < 8; ++i) {
            if (m8[i]) {
                cum++;
                if (cum == split) minfo[b * 8 + 2] = s0 + i;
                if (cum == total) minfo[b * 8 + 3] = s0 + i;
            }
        }
        if (tid == 0) { minfo[b * 8 + 0] = total; minfo[b * 8 + 1] = split; }
    }
}

// ---------------- single heavy pass over x ----------------
// grid (64,16); block = 128 tokens; 4 waves read the same tokens (L1 broadcast),
// wave w owns heads {2w,2w+1}. Lane owns 8 contiguous cols. Pair-wise token loop
// with one-pair prefetch. Score reduction via DPP (VALU) — zero DS ops in loop.
// Masks via one __ballot per 64-token half. Flush = direct stores to part buffer.
__global__ __launch_bounds__(256, 4) void k_main(const float* __restrict__ x,
                                                 const int* __restrict__ mask,
                                                 const float* __restrict__ wkeff,
                                                 const int* __restrict__ minfo,
                                                 float* __restrict__ xpart,
                                                 float* __restrict__ lpart) {
    const int b = blockIdx.x, chunk = blockIdx.y;
    const int tid = threadIdx.x, hg = tid >> 6, lane = tid & 63;
    const int h0 = hg * 2;
    const int col0 = lane * 8;

    float wk0[8], wk1[8];
    #pragma unroll
    for (int i = 0; i < 8; ++i) {
        wk0[i] = wkeff[h0 * 512 + col0 + i];
        wk1[i] = wkeff[(h0 + 1) * 512 + col0 + i];
    }

    const int boundary = minfo[b * 8 + 2];
    const int sb = chunk * 128;
    const int* mb = mask + b * S_;
    unsigned long long bm0 = __ballot(mb[sb + lane] > 0);
    unsigned long long bm1 = __ballot(mb[sb + 64 + lane] > 0);

    float acc0[8], acc1[8], sacc[8], pacc[8];
    #pragma unroll
    for (int i = 0; i < 8; ++i) { acc0[i] = 0.f; acc1[i] = 0.f; sacc[i] = 0.f; pacc[i] = 0.f; }
    float l0 = 0.f, l1 = 0.f;

    const float* base = x + (size_t)b * (S_ * D_) + (size_t)sb * D_ + col0;
    float4 A0 = *(const float4*)(base);
    float4 A1 = *(const float4*)(base + 4);
    float4 B0 = *(const float4*)(base + D_);
    float4 B1 = *(const float4*)(base + D_ + 4);

    for (int t = 0; t < 128; t += 2) {
        float xa8[8] = {A0.x, A0.y, A0.z, A0.w, A1.x, A1.y, A1.z, A1.w};
        float xb8[8] = {B0.x, B0.y, B0.z, B0.w, B1.x, B1.y, B1.z, B1.w};
        if (t + 2 < 128) {
            const float* nb = base + (size_t)(t + 2) * D_;
            A0 = *(const float4*)(nb);
            A1 = *(const float4*)(nb + 4);
            B0 = *(const float4*)(nb + D_);
            B1 = *(const float4*)(nb + D_ + 4);
        }
        // per-lane partial scores: 2 tokens x 2 heads
        float s00 = xa8[0] * wk0[0], s01 = xa8[0] * wk1[0];
        float s10 = xb8[0] * wk0[0], s11 = xb8[0] * wk1[0];
        #pragma unroll
        for (int i = 1; i < 8; ++i) {
            s00 = fmaf(xa8[i], wk0[i], s00);
            s01 = fmaf(xa8[i], wk1[i], s01);
            s10 = fmaf(xb8[i], wk0[i], s10);
            s11 = fmaf(xb8[i], wk1[i], s11);
        }
        // VALU-pipe wave reduction (DPP), wave-uniform results
        float f00 = wave_sum64(s00);
        float f01 = wave_sum64(s01);
        float f10 = wave_sum64(s10);
        float f11 = wave_sum64(s11);

        unsigned long long bsel = (t < 64) ? bm0 : bm1;
        bool mm0 = ((bsel >> (t & 63)) & 1ULL) != 0;
        bool mm1 = ((bsel >> ((t + 1) & 63)) & 1ULL) != 0;

        float w00 = mm0 ? __expf(f00) : 0.f;
        float w01 = mm0 ? __expf(f01) : 0.f;
        float w10 = mm1 ? __expf(f10) : 0.f;
        float w11 = mm1 ? __expf(f11) : 0.f;
        l0 += w00 + w10;
        l1 += w01 + w11;
        #pragma unroll
        for (int i = 0; i < 8; ++i) {
            acc0[i] = fmaf(w10, xb8[i], fmaf(w00, xa8[i], acc0[i]));
            acc1[i] = fmaf(w11, xb8[i], fmaf(w01, xa8[i], acc1[i]));
        }
        if (hg == 0) {
            int sg0 = sb + t, sg1 = sb + t + 1;
            float fs0 = (mm0 && sg0 <= boundary) ? 1.f : 0.f;
            float fp0 = (mm0 && sg0 >  boundary) ? 1.f : 0.f;
            float fs1 = (mm1 && sg1 <= boundary) ? 1.f : 0.f;
            float fp1 = (mm1 && sg1 >  boundary) ? 1.f : 0.f;
            #pragma unroll
            for (int i = 0; i < 8; ++i) {
                sacc[i] = fmaf(fs1, xb8[i], fmaf(fs0, xa8[i], sacc[i]));
                pacc[i] = fmaf(fp1, xb8[i], fmaf(fp0, xa8[i], pacc[i]));
            }
        }
    }

    // direct stores: wave owns rows h0,h0+1 of this chunk's part block exclusively
    float* pbase = xpart + ((size_t)(b * 16 + chunk) * 10) * 512;
    float* d0 = pbase + (size_t)h0 * 512 + col0;
    float* d1 = d0 + 512;
    ((float4*)d0)[0] = make_float4(acc0[0], acc0[1], acc0[2], acc0[3]);
    ((float4*)d0)[1] = make_float4(acc0[4], acc0[5], acc0[6], acc0[7]);
    ((float4*)d1)[0] = make_float4(acc1[0], acc1[1], acc1[2], acc1[3]);
    ((float4*)d1)[1] = make_float4(acc1[4], acc1[5], acc1[6], acc1[7]);
    if (hg == 0) {
        float* ds = pbase + 8 * 512 + col0;
        float* dp = pbase + 9 * 512 + col0;
        ((float4*)ds)[0] = make_float4(sacc[0], sacc[1], sacc[2], sacc[3]);
        ((float4*)ds)[1] = make_float4(sacc[4], sacc[5], sacc[6], sacc[7]);
        ((float4*)dp)[0] = make_float4(pacc[0], pacc[1], pacc[2], pacc[3]);
        ((float4*)dp)[1] = make_float4(pacc[4], pacc[5], pacc[6], pacc[7]);
    }
    if (lane == 0) {
        lpart[(b * 16 + chunk) * 8 + h0]     = l0;   // l0/l1 are wave-uniform
        lpart[(b * 16 + chunk) * 8 + h0 + 1] = l1;
    }
}

// reduce part buffer over 16 chunks. grid (64, 10, 2), 256 thr.
// rows 0..7 -> xa raw; row 8 -> ssum; row 9 -> psum.
__global__ __launch_bounds__(256) void k_xared(const float* __restrict__ part,
                                               float* __restrict__ xa,
                                               float* __restrict__ ssum,
                                               float* __restrict__ psum) {
    int b = blockIdx.x, r = blockIdx.y;
    int e = blockIdx.z * 256 + threadIdx.x;
    float s = 0.f;
    #pragma unroll
    for (int c = 0; c < 16; ++c)
        s += part[(((size_t)(b * 16 + c)) * 10 + r) * 512 + e];
    if (r < 8)       xa[((size_t)b * 8 + r) * 512 + e] = s;
    else if (r == 8) ssum[b * 512 + e] = s;
    else             psum[b * 512 + e] = s;
}

// mean_tok, setup_mean, punch_mean (punch_cnt==0 -> last valid token), clost_stream
__global__ __launch_bounds__(256) void k_means(const float* __restrict__ x,
                                               const float* __restrict__ ssum,
                                               const float* __restrict__ psum,
                                               const int* __restrict__ minfo,
                                               float* __restrict__ meantok,
                                               float* __restrict__ catsp,
                                               float* __restrict__ clost) {
    int b = blockIdx.x;
    int e = blockIdx.y * 256 + threadIdx.x;
    int total = minfo[b * 8 + 0], split = minfo[b * 8 + 1], last = minfo[b * 8 + 3];
    int pcnt = total - split;
    float ssv = ssum[b * 512 + e], psv = psum[b * 512 + e];
    float mt = (ssv + psv) / (float)total;
    float sm = ssv / (float)split;
    float pm = (pcnt > 0) ? psv / (float)pcnt : x[((size_t)b * S_ + last) * D_ + e];
    meantok[b * 512 + e] = mt;
    catsp[b * 1024 + e] = sm;
    catsp[b * 1024 + 512 + e] = pm;
    clost[b * 512 + e] = 0.5f * (sm + pm);
}

// ---------------- batched GEMV: up to 3 ops per launch (blockIdx.z) ----------------
// grid (64, 8, nz). Block: batch b, 64 outputs, 4-way K-split (256 thr).
// A row staged in LDS; headmode: A row = xa[b, head=jg] * (1/sum_c lpart[b,c,jg]).
__global__ __launch_bounds__(256) void k_gemv3(
    const float* lpart,
    const float* A0_, int lda0, const float* W0_, const float* bi0_, float* o0_, int K0, int r0, int hm0,
    const float* A1_, int lda1, const float* W1_, const float* bi1_, float* o1_, int K1, int r1, int hm1,
    const float* A2_, int lda2, const float* W2_, const float* bi2_, float* o2_, int K2, int r2, int hm2) {
    const float* A; const float* W; const float* bias; float* out;
    int lda, K, relu_, hm;
    int z = blockIdx.z;
    if (z == 0)      { A = A0_; lda = lda0; W = W0_; bias = bi0_; out = o0_; K = K0; relu_ = r0; hm = hm0; }
    else if (z == 1) { A = A1_; lda = lda1; W = W1_; bias = bi1_; out = o1_; K = K1; relu_ = r1; hm = hm1; }
    else             { A = A2_; lda = lda2; W = W2_; bias = bi2_; out = o2_; K = K2; relu_ = r2; hm = hm2; }

    int b = blockIdx.x, jg = blockIdx.y;
    int tid = threadIdx.x, jl = tid & 63, part = tid >> 6;
    int j = jg * 64 + jl;
    const float* a = hm ? (A + ((size_t)(b * 8 + jg)) * 512) : (A + (size_t)b * lda);
    float scale = 1.f;
    if (hm) {
        float lsum = 0.f;
        #pragma unroll
        for (int c = 0; c < 16; ++c) lsum += lpart[(b * 16 + c) * 8 + jg];
        scale = 1.f / lsum;
    }

    __shared__ float sha[1024];
    for (int e = tid; e < K; e += 256) sha[e] = a[e] * scale;
    __syncthreads();

    int Kq = (K + 3) >> 2;
    int e0 = part * Kq, e1 = min(K, e0 + Kq);
    float acc = 0.f;
    int e = e0;
    for (; e + 8 <= e1; e += 8) {
        #pragma unroll
        for (int u = 0; u < 8; ++u)
            acc = fmaf(sha[e + u], W[(size_t)(e + u) * 512 + j], acc);
    }
    for (; e < e1; ++e) acc = fmaf(sha[e], W[(size_t)e * 512 + j], acc);

    __shared__ float shr[256];
    shr[tid] = acc;
    __syncthreads();
    if (part == 0) {
        float s = shr[jl] + shr[jl + 64] + shr[jl + 128] + shr[jl + 192];
        if (bias) s += bias[j];
        if (relu_) s = fmaxf(s, 0.f);
        out[(size_t)b * 512 + j] = s;
    }
}

// fused: scalar heads (tom_hp/inc/clost_prob) + stream mixing + headin build
__global__ __launch_bounds__(256) void k_scalmix(const float* __restrict__ fm,
                                                 const float* __restrict__ ctx,
                                                 const float* __restrict__ hc,
                                                 const float* __restrict__ clost,
                                                 const float* __restrict__ w_hp,  const float* __restrict__ b_hp,
                                                 const float* __restrict__ w_inc, const float* __restrict__ b_inc,
                                                 const float* __restrict__ wc2,   const float* __restrict__ bc2,
                                                 const float* __restrict__ U,
                                                 const float* __restrict__ V,
                                                 float* __restrict__ s3,
                                                 float* __restrict__ headin) {
    int b = blockIdx.x, tid = threadIdx.x;
    float a0 = 0.f, a1 = 0.f, a2 = 0.f;
    for (int e = tid; e < 512; e += 256) {
        a0 = fmaf(fm[b * 512 + e],  w_hp[e],  a0);
        a1 = fmaf(ctx[b * 512 + e], w_inc[e], a1);
        a2 = fmaf(hc[b * 512 + e],  wc2[e],   a2);
    }
    __shared__ float r[3][256];
    r[0][tid] = a0; r[1][tid] = a1; r[2][tid] = a2;
    __syncthreads();
    for (int off = 128; off > 0; off >>= 1) {
        if (tid < off) {
            r[0][tid] += r[0][tid + off];
            r[1][tid] += r[1][tid + off];
            r[2][tid] += r[2][tid + off];
        }
        __syncthreads();
    }
    __shared__ float s3sh[3];
    if (tid == 0) {
        s3sh[0] = 1.f / (1.f + __expf(-(r[0][0] + b_hp[0])));
        s3sh[1] = 1.f / (1.f + __expf(-(r[1][0] + b_inc[0])));
        s3sh[2] = 1.f / (1.f + __expf(-(r[2][0] + bc2[0])));
        s3[b * 4 + 0] = s3sh[0];
        s3[b * 4 + 1] = s3sh[1];
        s3[b * 4 + 2] = s3sh[2];
    }
    __syncthreads();
    float M3[3][3];
    #pragma unroll
    for (int s = 0; s < 3; ++s)
        #pragma unroll
        for (int t = 0; t < 3; ++t) {
            float acc = (s == t) ? 1.f : 0.f;
            #pragma unroll
            for (int r4 = 0; r4 < 4; ++r4) acc = fmaf(U[s * 4 + r4], V[r4 * 3 + t], acc);
            M3[s][t] = acc;
        }
    float mx[3][2];
    #pragma unroll
    for (int kk = 0; kk < 2; ++kk) {
        int e = tid + kk * 256;
        float t0 = fm[b * 512 + e], t1 = ctx[b * 512 + e], t2 = clost[b * 512 + e];
        #pragma unroll
        for (int s = 0; s < 3; ++s) mx[s][kk] = M3[s][0] * t0 + M3[s][1] * t1 + M3[s][2] * t2;
    }
    #pragma unroll
    for (int s = 0; s < 3; ++s) r[s][tid] = mx[s][0] * mx[s][0] + mx[s][1] * mx[s][1];
    __syncthreads();
    for (int off = 128; off > 0; off >>= 1) {
        if (tid < off) {
            r[0][tid] += r[0][tid + off];
            r[1][tid] += r[1][tid + off];
            r[2][tid] += r[2][tid + off];
        }
        __syncthreads();
    }
    __shared__ float nrm[3];
    if (tid < 3) nrm[tid] = sqrtf(r[tid][0]) + 1e-6f;
    __syncthreads();
    #pragma unroll
    for (int kk = 0; kk < 2; ++kk) {
        int e = tid + kk * 256;
        float p = (mx[0][kk] / nrm[0] + mx[1][kk] / nrm[1] + mx[2][kk] / nrm[2]) * (1.f / 3.f);
        headin[b * 520 + e] = p;
    }
    if (tid < 3) headin[b * 520 + 512 + tid] = s3sh[tid];
}

__global__ __launch_bounds__(256) void k_logit(const float* __restrict__ hs,
                                               const float* __restrict__ hf,
                                               const float* __restrict__ ws2, const float* __restrict__ bs2,
                                               const float* __restrict__ wf2, const float* __restrict__ bf2,
                                               const float* __restrict__ s3,
                                               float* __restrict__ out) {
    int b = blockIdx.x, tid = threadIdx.x;
    float a = 0.f, c = 0.f;
    for (int e = tid; e < 512; e += 256) {
        a = fmaf(hs[b * 512 + e], ws2[e], a);
        c = fmaf(hf[b * 512 + e], wf2[e], c);
    }
    __shared__ float r[2][256];
    r[0][tid] = a; r[1][tid] = c;
    __syncthreads();
    for (int off = 128; off > 0; off >>= 1) {
        if (tid < off) { r[0][tid] += r[0][tid + off]; r[1][tid] += r[1][tid + off]; }
        __syncthreads();
    }
    if (tid == 0) {
        float sev = r[0][0] + bs2[0];
        float fl  = r[1][0] + bf2[0];
        float p = (s3[b * 4] + s3[b * 4 + 1] + s3[b * 4 + 2]) * (1.f / 3.f);
        p = fminf(fmaxf(p, 1e-4f), 1.f - 1e-4f);
        out[b] = fl + 0.5f * sev + 0.1f * logf(p / (1.f - p));
    }
}

extern "C" void kernel_launch(void* const* d_in, const int* in_sizes, int n_in,
                              void* d_out, int out_size, void* d_ws, size_t ws_size,
                              hipStream_t stream) {
    const float* x     = (const float*)d_in[0];
    const int*   mask  = (const int*)d_in[1];
    const float* Wk    = (const float*)d_in[2];
    const float* Wv    = (const float*)d_in[3];
    const float* q_tom = (const float*)d_in[4];
    const float* Wtf   = (const float*)d_in[5];
    const float* w_hp  = (const float*)d_in[6];
    const float* b_hp  = (const float*)d_in[7];
    const float* Wg1   = (const float*)d_in[8];
    const float* bg1   = (const float*)d_in[9];
    const float* Wg2   = (const float*)d_in[10];
    const float* bg2   = (const float*)d_in[11];
    const float* w_inc = (const float*)d_in[12];
    const float* b_inc = (const float*)d_in[13];
    const float* Wc1   = (const float*)d_in[14];
    const float* bc1   = (const float*)d_in[15];
    const float* wc2   = (const float*)d_in[16];
    const float* bc2   = (const float*)d_in[17];
    const float* U     = (const float*)d_in[18];
    const float* V     = (const float*)d_in[19];
    const float* Ws1   = (const float*)d_in[20];
    const float* bs1   = (const float*)d_in[21];
    const float* ws2   = (const float*)d_in[22];
    const float* bs2   = (const float*)d_in[23];
    const float* Wf1   = (const float*)d_in[24];
    const float* bf1   = (const float*)d_in[25];
    const float* wf2   = (const float*)d_in[26];
    const float* bf2   = (const float*)d_in[27];

    float* ws      = (float*)d_ws;
    float* wkeff   = ws + OFF_WKEFF;
    float* xpart   = ws + OFF_XPART;
    float* lpart   = ws + OFF_LPART;
    float* xa      = ws + OFF_XA;
    float* ssum    = ws + OFF_SSUM;
    float* psum    = ws + OFF_PSUM;
    float* fused   = ws + OFF_FUSED;
    float* fm      = ws + OFF_FM;
    float* meantok = ws + OFF_MEANT;
    float* catsp   = ws + OFF_CATSP;
    float* clost   = ws + OFF_CLOST;
    float* g1      = ws + OFF_G1;
    float* ctxb    = ws + OFF_CTX;
    float* hc      = ws + OFF_HC;
    float* s3      = ws + OFF_S3;
    float* headin  = ws + OFF_HEADIN;
    float* hsb     = ws + OFF_HS;
    float* hfb     = ws + OFF_HF;
    int*   minfo   = (int*)(ws + OFF_MINFO);
    float* out     = (float*)d_out;

    hipLaunchKernelGGL(k_prep,   dim3(80),        dim3(256), 0, stream, Wk, q_tom, mask, wkeff, minfo);
    hipLaunchKernelGGL(k_main,   dim3(64, 16),    dim3(256), 0, stream, x, mask, wkeff, minfo,
                       xpart, lpart);
    hipLaunchKernelGGL(k_xared,  dim3(64, 10, 2), dim3(256), 0, stream, xpart, xa, ssum, psum);
    hipLaunchKernelGGL(k_means,  dim3(64, 2),     dim3(256), 0, stream, x, ssum, psum, minfo,
                       meantok, catsp, clost);
    // stage A: fused = (xa/l)@Wv ; g1 = relu(meantok@Wg1+bg1) ; hc = relu(catsp@Wc1+bc1)
    hipLaunchKernelGGL(k_gemv3,  dim3(64, 8, 3),  dim3(256), 0, stream, lpart,
                       xa, 0, Wv, (const float*)nullptr, fused, 512, 0, 1,
                       meantok, 512, Wg1, bg1, g1, 512, 1, 0,
                       catsp, 1024, Wc1, bc1, hc, 1024, 1, 0);
    // stage B: fm = fused@Wtf ; ctx = g1@Wg2+bg2
    hipLaunchKernelGGL(k_gemv3,  dim3(64, 8, 2),  dim3(256), 0, stream, lpart,
                       fused, 512, Wtf, (const float*)nullptr, fm, 512, 0, 0,
                       g1, 512, Wg2, bg2, ctxb, 512, 0, 0,
                       (const float*)nullptr, 0, (const float*)nullptr, (const float*)nullptr,
                       (float*)nullptr, 0, 0, 0);
    hipLaunchKernelGGL(k_scalmix, dim3(64),       dim3(256), 0, stream, fm, ctxb, hc, clost,
                       w_hp, b_hp, w_inc, b_inc, wc2, bc2, U, V, s3, headin);
    // stage D: hs = relu(headin@Ws1+bs1) ; hf = relu(headin@Wf1+bf1)
    hipLaunchKernelGGL(k_gemv3,  dim3(64, 8, 2),  dim3(256), 0, stream, lpart,
                       headin, 520, Ws1, bs1, hsb, 515, 1, 0,
                       headin, 520, Wf1, bf1, hfb, 515, 1, 0,
                       (const float*)nullptr, 0, (const float*)nullptr, (const float*)nullptr,
                       (float*)nullptr, 0, 0, 0);
    hipLaunchKernelGGL(k_logit,  dim3(64),        dim3(256), 0, stream, hsb, hfb, ws2, bs2, wf2, bf2, s3, out);
}